// Round 2
// baseline (9110.693 us; speedup 1.0000x reference)
//
#include <hip/hip_runtime.h>
#include <hip/hip_bf16.h>

#define B_    16
#define FEA_  512
#define DM_   1024
#define HALF_ 512
#define DFF_  2048

typedef unsigned short u16;

__device__ __forceinline__ float bf2f(u16 u) {
  union { unsigned int i; float f; } v; v.i = ((unsigned int)u) << 16; return v.f;
}
__device__ __forceinline__ u16 f2bf(float f) {
  union { float f; unsigned int i; } v; v.f = f;
  unsigned int x = v.i;
  return (u16)((x + 0x7fffu + ((x >> 16) & 1u)) >> 16);
}

// ---------------- DWT (Haar, level 1, last axis) ----------------
__global__ void dwt_kernel(const float* __restrict__ x, u16* __restrict__ x1,
                           u16* __restrict__ x2, int n) {
  int i = blockIdx.x * 256 + threadIdx.x;
  if (i >= n) return;
  float2 v = ((const float2*)x)[i];
  x1[i] = f2bf((v.x + v.y) * 0.70710678118f);
  x2[i] = f2bf((v.x - v.y) * 0.70710678118f);
}

// ---------------- weight transpose (Cout,Cin,3) -> (3,Cout,Cin) ----------------
__global__ void wtrans_kernel(const float* __restrict__ w, float* __restrict__ wt,
                              int Cout, int Cin) {
  int e = blockIdx.x * 256 + threadIdx.x;
  if (e >= Cout * Cin * 3) return;
  int co = e / (Cin * 3);
  int r  = e - co * Cin * 3;
  int ci = r / 3;
  int t  = r - ci * 3;
  wt[((size_t)t * Cout + co) * Cin + ci] = w[e];
}

// ---------------- generic circular conv1d (k=3) as tiled GEMM ----------------
// Z: bf16 [b][l][ci] (L x Cin per batch), Wt: f32 [3][Cout][Cin], out bf16 with
// strides: out[b*L*Cout + l*osl + co*osc]
__global__ __launch_bounds__(256, 2) void conv_kernel(
    const u16* __restrict__ Z, const float* __restrict__ Wt,
    const float* __restrict__ bias, u16* __restrict__ out,
    int L, int Cin, int Cout, int osl, int osc, int relu) {
  __shared__ float Zs[66][68];
  __shared__ float Ws[3][64][68];
  int l0 = blockIdx.x * 64, co0 = blockIdx.y * 64, b = blockIdx.z;
  int tid = threadIdx.x, ty = tid >> 4, tx = tid & 15;
  float acc[4][4] = {{0.f, 0.f, 0.f, 0.f}};
  const u16* Zb = Z + (size_t)b * L * Cin;
  for (int c0 = 0; c0 < Cin; c0 += 64) {
    for (int e = tid; e < 66 * 16; e += 256) {
      int r = e >> 4, q4 = e & 15;
      int gl = l0 + r - 1;
      if (gl < 0) gl += L; else if (gl >= L) gl -= L;
      ushort4 u = *(const ushort4*)(Zb + (size_t)gl * Cin + c0 + q4 * 4);
      float4 f; f.x = bf2f(u.x); f.y = bf2f(u.y); f.z = bf2f(u.z); f.w = bf2f(u.w);
      *(float4*)&Zs[r][q4 * 4] = f;
    }
    for (int e = tid; e < 3 * 64 * 16; e += 256) {
      int t = e >> 10, rem = e & 1023, j = rem >> 4, q4 = rem & 15;
      *(float4*)&Ws[t][j][q4 * 4] =
          *(const float4*)(Wt + ((size_t)t * Cout + co0 + j) * Cin + c0 + q4 * 4);
    }
    __syncthreads();
    for (int k = 0; k < 64; k += 4) {
      float4 w[3][4];
#pragma unroll
      for (int t = 0; t < 3; ++t)
#pragma unroll
        for (int j = 0; j < 4; ++j) w[t][j] = *(float4*)&Ws[t][tx + 16 * j][k];
#pragma unroll
      for (int i = 0; i < 4; ++i) {
        float4 z0 = *(float4*)&Zs[ty + 16 * i][k];
        float4 z1 = *(float4*)&Zs[ty + 16 * i + 1][k];
        float4 z2 = *(float4*)&Zs[ty + 16 * i + 2][k];
#pragma unroll
        for (int j = 0; j < 4; ++j) {
          float a = acc[i][j];
          a += z0.x * w[0][j].x; a += z1.x * w[1][j].x; a += z2.x * w[2][j].x;
          a += z0.y * w[0][j].y; a += z1.y * w[1][j].y; a += z2.y * w[2][j].y;
          a += z0.z * w[0][j].z; a += z1.z * w[1][j].z; a += z2.z * w[2][j].z;
          a += z0.w * w[0][j].w; a += z1.w * w[1][j].w; a += z2.w * w[2][j].w;
          acc[i][j] = a;
        }
      }
    }
    __syncthreads();
  }
#pragma unroll
  for (int i = 0; i < 4; ++i)
#pragma unroll
    for (int j = 0; j < 4; ++j) {
      int l = l0 + ty + 16 * i, co = co0 + tx + 16 * j;
      float v = acc[i][j] + bias[co];
      if (relu) v = fmaxf(v, 0.f);
      out[(size_t)b * L * Cout + (size_t)l * osl + (size_t)co * osc] = f2bf(v);
    }
}

// ---------------- fused cross attention ----------------
// grid: (qtile 16, head 16, b*2+branch 32), block 256
// branch 0: Q=qh K=kl V=vh -> cf in [0,512); branch 1: Q=ql K=kh V=vl -> cf in [512,1024)
// writes ctx bf16 [b][d (1024)][cf (1024)]
__global__ __launch_bounds__(256, 2) void attn_kernel(
    const u16* __restrict__ qh, const u16* __restrict__ kh, const u16* __restrict__ vh,
    const u16* __restrict__ ql, const u16* __restrict__ kl, const u16* __restrict__ vl,
    u16* __restrict__ ctx) {
  __shared__ float Qs[32][68];
  __shared__ float KVs[64][68];
  __shared__ u16 Ps[32][520];
  __shared__ float rowsum[32];
  int qt = blockIdx.x, h = blockIdx.y, bz = blockIdx.z;
  int b = bz >> 1, br = bz & 1;
  const u16* Q = br ? ql : qh;
  const u16* K = br ? kh : kl;
  const u16* V = br ? vl : vh;
  size_t base = ((size_t)b * FEA_) * DM_ + h * 64;
  int q0 = qt * 32;
  int tid = threadIdx.x, ty = tid >> 4, tx = tid & 15;
  for (int e = tid; e < 32 * 16; e += 256) {
    int r = e >> 4, q4 = e & 15;
    ushort4 u = *(const ushort4*)(Q + base + (size_t)(q0 + r) * DM_ + q4 * 4);
    float4 f; f.x = bf2f(u.x); f.y = bf2f(u.y); f.z = bf2f(u.z); f.w = bf2f(u.w);
    *(float4*)&Qs[r][q4 * 4] = f;
  }
  float rs[2] = {0.f, 0.f};
  for (int kt = 0; kt < 8; ++kt) {
    __syncthreads();
    for (int e = tid; e < 64 * 16; e += 256) {
      int r = e >> 4, q4 = e & 15;
      ushort4 u = *(const ushort4*)(K + base + (size_t)(kt * 64 + r) * DM_ + q4 * 4);
      float4 f; f.x = bf2f(u.x); f.y = bf2f(u.y); f.z = bf2f(u.z); f.w = bf2f(u.w);
      *(float4*)&KVs[r][q4 * 4] = f;
    }
    __syncthreads();
    float s[2][4] = {{0.f, 0.f, 0.f, 0.f}};
    for (int d = 0; d < 64; d += 4) {
      float4 qv0 = *(float4*)&Qs[ty][d];
      float4 qv1 = *(float4*)&Qs[ty + 16][d];
#pragma unroll
      for (int j = 0; j < 4; ++j) {
        float4 kv = *(float4*)&KVs[tx + 16 * j][d];
        s[0][j] += qv0.x * kv.x + qv0.y * kv.y + qv0.z * kv.z + qv0.w * kv.w;
        s[1][j] += qv1.x * kv.x + qv1.y * kv.y + qv1.z * kv.z + qv1.w * kv.w;
      }
    }
#pragma unroll
    for (int i = 0; i < 2; ++i)
#pragma unroll
      for (int j = 0; j < 4; ++j) {
        float p = __expf(s[i][j] * 0.25f);  // scale = 1/sqrt(n_heads)
        Ps[ty + 16 * i][kt * 64 + tx + 16 * j] = f2bf(p);
        rs[i] += p;
      }
  }
#pragma unroll
  for (int i = 0; i < 2; ++i) {
#pragma unroll
    for (int m = 1; m < 16; m <<= 1) rs[i] += __shfl_xor(rs[i], m);
    if (tx == 0) rowsum[ty + 16 * i] = rs[i];
  }
  float o[2][4] = {{0.f, 0.f, 0.f, 0.f}};
  for (int kt = 0; kt < 8; ++kt) {
    __syncthreads();
    for (int e = tid; e < 64 * 16; e += 256) {
      int r = e >> 4, q4 = e & 15;
      ushort4 u = *(const ushort4*)(V + base + (size_t)(kt * 64 + r) * DM_ + q4 * 4);
      KVs[q4 * 4 + 0][r] = bf2f(u.x);
      KVs[q4 * 4 + 1][r] = bf2f(u.y);
      KVs[q4 * 4 + 2][r] = bf2f(u.z);
      KVs[q4 * 4 + 3][r] = bf2f(u.w);
    }
    __syncthreads();
    for (int kc = 0; kc < 64; kc += 4) {
      ushort4 pu0 = *(const ushort4*)&Ps[ty][kt * 64 + kc];
      ushort4 pu1 = *(const ushort4*)&Ps[ty + 16][kt * 64 + kc];
#pragma unroll
      for (int j = 0; j < 4; ++j) {
        float4 vv = *(float4*)&KVs[tx + 16 * j][kc];
        o[0][j] += bf2f(pu0.x) * vv.x + bf2f(pu0.y) * vv.y + bf2f(pu0.z) * vv.z + bf2f(pu0.w) * vv.w;
        o[1][j] += bf2f(pu1.x) * vv.x + bf2f(pu1.y) * vv.y + bf2f(pu1.z) * vv.z + bf2f(pu1.w) * vv.w;
      }
    }
  }
  __syncthreads();
  float inv0 = 1.0f / rowsum[ty];
  float inv1 = 1.0f / rowsum[ty + 16];
#pragma unroll
  for (int i = 0; i < 2; ++i) {
    float inv = i ? inv1 : inv0;
#pragma unroll
    for (int j = 0; j < 4; ++j) {
      int d = h * 64 + tx + 16 * j;
      int cf = br * 512 + q0 + ty + 16 * i;
      ctx[((size_t)b * DM_ + d) * (2 * FEA_) + cf] = f2bf(o[i][j] * inv);
    }
  }
}

// ---------------- LayerNorm over last axis (+optional f32 residual out) ----------------
template <int RESID>
__global__ void ln_kernel(const u16* __restrict__ in, const float* __restrict__ g,
                          const float* __restrict__ beta, const float* __restrict__ resid,
                          void* __restrict__ outp, int C) {
  int row = blockIdx.x;
  int tid = threadIdx.x;
  const u16* p = in + (size_t)row * C;
  float s = 0.f, ss = 0.f;
  for (int c = tid; c < C; c += 256) {
    float v = bf2f(p[c]);
    s += v; ss += v * v;
  }
#pragma unroll
  for (int m = 1; m < 64; m <<= 1) { s += __shfl_xor(s, m); ss += __shfl_xor(ss, m); }
  __shared__ float red[2][4];
  int wid = tid >> 6, lane = tid & 63;
  if (lane == 0) { red[0][wid] = s; red[1][wid] = ss; }
  __syncthreads();
  s  = red[0][0] + red[0][1] + red[0][2] + red[0][3];
  ss = red[1][0] + red[1][1] + red[1][2] + red[1][3];
  float m  = s / C;
  float var = ss / C - m * m;
  float inv = rsqrtf(var + 1e-5f);
  for (int c = tid; c < C; c += 256) {
    float v = (bf2f(p[c]) - m) * inv * g[c] + beta[c];
    if (RESID) ((float*)outp)[(size_t)row * C + c] = v + resid[(size_t)row * C + c];
    else       ((u16*)outp)[(size_t)row * C + c]   = f2bf(v);
  }
}

extern "C" void kernel_launch(void* const* d_in, const int* in_sizes, int n_in,
                              void* d_out, int out_size, void* d_ws, size_t ws_size,
                              hipStream_t stream) {
  (void)in_sizes; (void)n_in; (void)out_size; (void)ws_size;
  const float* x      = (const float*)d_in[0];
  const float* Wq     = (const float*)d_in[1];
  const float* bq     = (const float*)d_in[2];
  const float* Wk     = (const float*)d_in[3];
  const float* bk     = (const float*)d_in[4];
  const float* Wv     = (const float*)d_in[5];
  const float* bv     = (const float*)d_in[6];
  const float* uns_w  = (const float*)d_in[7];
  const float* uns_b  = (const float*)d_in[8];
  const float* cv_w1  = (const float*)d_in[9];
  const float* cv_b1  = (const float*)d_in[10];
  const float* cv_w2  = (const float*)d_in[11];
  const float* cv_b2  = (const float*)d_in[12];
  const float* cv_g   = (const float*)d_in[13];
  const float* cv_beta= (const float*)d_in[14];
  const float* up_w1  = (const float*)d_in[15];
  const float* up_b1  = (const float*)d_in[16];
  const float* up_w2  = (const float*)d_in[17];
  const float* up_b2  = (const float*)d_in[18];
  const float* up_g   = (const float*)d_in[19];
  const float* up_beta= (const float*)d_in[20];

  // ---- tight workspace plan: peak 112 MiB of d_ws; d_out doubles as scratch ----
  // phase 1 (dwt+proj):  x1[0,8) x2[8,16) qkv[16,112)  wt_proj = d_out
  // phase 2 (attn):      reads qkv, writes ctx = d_out (32 MiB, exact fit)
  // phase 3 (uns):       wt_uns[0,8)   ctx2[16,32)
  // phase 4 (cv):        wt_cv1[32,56) h1[56,88) ; wt_cv2[32,48) h2[0,8) ; ctx3[8,16)
  // phase 5 (up):        wt_up1[16,29) h3[32,64) ; wt_up2[64,88) h4[16,32)
  // phase 6 (ln+resid):  reads h4 + x, writes d_out (ctx dead)
  char* ws = (char*)d_ws;
  const size_t MB = 1ull << 20;
  u16* x1    = (u16*)(ws + 0);
  u16* x2    = (u16*)(ws + 8 * MB);
  u16* qhb   = (u16*)(ws + 16 * MB);
  u16* khb   = (u16*)(ws + 32 * MB);
  u16* vhb   = (u16*)(ws + 48 * MB);
  u16* qlb   = (u16*)(ws + 64 * MB);
  u16* klb   = (u16*)(ws + 80 * MB);
  u16* vlb   = (u16*)(ws + 96 * MB);
  float* wt_proj = (float*)d_out;      // 6.29 MiB used, dead before attn writes ctx
  u16* ctx   = (u16*)d_out;            // 32 MiB, dead before final ln writes d_out
  float* wt_uns = (float*)(ws + 0);
  u16* ctx2  = (u16*)(ws + 16 * MB);
  float* wt_cv1 = (float*)(ws + 32 * MB);
  u16* h1    = (u16*)(ws + 56 * MB);
  float* wt_cv2 = (float*)(ws + 32 * MB);
  u16* h2    = (u16*)(ws + 0);
  u16* ctx3  = (u16*)(ws + 8 * MB);
  float* wt_up1 = (float*)(ws + 16 * MB);
  u16* h3    = (u16*)(ws + 32 * MB);
  float* wt_up2 = (float*)(ws + 64 * MB);
  u16* h4    = (u16*)(ws + 16 * MB);

  dwt_kernel<<<(B_ * FEA_ * HALF_ + 255) / 256, 256, 0, stream>>>(x, x1, x2, B_ * FEA_ * HALF_);

  auto wtr = [&](const float* w, float* wt, int Cout, int Cin) {
    wtrans_kernel<<<(Cout * Cin * 3 + 255) / 256, 256, 0, stream>>>(w, wt, Cout, Cin);
  };
  auto conv = [&](const u16* Z, const float* wt, const float* bias, u16* out, int L,
                  int Cin, int Cout, int osl, int osc, int relu) {
    conv_kernel<<<dim3(L / 64, Cout / 64, B_), 256, 0, stream>>>(Z, wt, bias, out, L, Cin,
                                                                 Cout, osl, osc, relu);
  };

  // projections (shared weights across both DWT branches)
  wtr(Wq, wt_proj, DM_, HALF_);
  conv(x1, wt_proj, bq, qhb, FEA_, HALF_, DM_, DM_, 1, 0);
  conv(x2, wt_proj, bq, qlb, FEA_, HALF_, DM_, DM_, 1, 0);
  wtr(Wk, wt_proj, DM_, HALF_);
  conv(x1, wt_proj, bk, khb, FEA_, HALF_, DM_, DM_, 1, 0);
  conv(x2, wt_proj, bk, klb, FEA_, HALF_, DM_, DM_, 1, 0);
  wtr(Wv, wt_proj, DM_, HALF_);
  conv(x1, wt_proj, bv, vhb, FEA_, HALF_, DM_, DM_, 1, 0);
  conv(x2, wt_proj, bv, vlb, FEA_, HALF_, DM_, DM_, 1, 0);

  attn_kernel<<<dim3(16, 16, 32), 256, 0, stream>>>(qhb, khb, vhb, qlb, klb, vlb, ctx);

  // unsqueeze conv: conv along d axis, channels 2F->F, transposed write -> ctx2[b][f][d]
  wtr(uns_w, wt_uns, FEA_, 2 * FEA_);
  conv(ctx, wt_uns, uns_b, ctx2, DM_, 2 * FEA_, FEA_, 1, DM_, 0);

  // Convlayer: D_MODEL -> D_FF -> HALF (conv along fea axis), then LN
  wtr(cv_w1, wt_cv1, DFF_, DM_);
  conv(ctx2, wt_cv1, cv_b1, h1, FEA_, DM_, DFF_, DFF_, 1, 1);
  wtr(cv_w2, wt_cv2, HALF_, DFF_);
  conv(h1, wt_cv2, cv_b2, h2, FEA_, DFF_, HALF_, HALF_, 1, 0);
  ln_kernel<0><<<B_ * FEA_, 256, 0, stream>>>(h2, cv_g, cv_beta, nullptr, ctx3, HALF_);

  // upsizeConvlayer: HALF -> D_FF -> D_MODEL, then LN + residual
  wtr(up_w1, wt_up1, DFF_, HALF_);
  conv(ctx3, wt_up1, up_b1, h3, FEA_, HALF_, DFF_, DFF_, 1, 1);
  wtr(up_w2, wt_up2, DM_, DFF_);
  conv(h3, wt_up2, up_b2, h4, FEA_, DFF_, DM_, DM_, 1, 0);
  ln_kernel<1><<<B_ * FEA_, 256, 0, stream>>>(h4, up_g, up_beta, x, d_out, DM_);
}

// Round 3
// 2424.095 us; speedup vs baseline: 3.7584x; 3.7584x over previous
//
#include <hip/hip_runtime.h>
#include <hip/hip_bf16.h>

#define B_    16
#define FEA_  512
#define DM_   1024
#define HALF_ 512
#define DFF_  2048

typedef unsigned short u16;
typedef __attribute__((ext_vector_type(8))) short bf16x8;
typedef __attribute__((ext_vector_type(4))) float f32x4;

__device__ __forceinline__ float bf2f(u16 u) {
  union { unsigned int i; float f; } v; v.i = ((unsigned int)u) << 16; return v.f;
}
__device__ __forceinline__ u16 f2bf(float f) {
  union { float f; unsigned int i; } v; v.f = f;
  unsigned int x = v.i;
  return (u16)((x + 0x7fffu + ((x >> 16) & 1u)) >> 16);
}

// ---------------- DWT (Haar, level 1, last axis) ----------------
__global__ void dwt_kernel(const float* __restrict__ x, u16* __restrict__ x1,
                           u16* __restrict__ x2, int n) {
  int i = blockIdx.x * 256 + threadIdx.x;
  if (i >= n) return;
  float2 v = ((const float2*)x)[i];
  x1[i] = f2bf((v.x + v.y) * 0.70710678118f);
  x2[i] = f2bf((v.x - v.y) * 0.70710678118f);
}

// ---------------- weight transpose (Cout,Cin,3) -> bf16 (3,Cout,Cin) ----------------
__global__ void wtrans_kernel(const float* __restrict__ w, u16* __restrict__ wt,
                              int Cout, int Cin) {
  int e = blockIdx.x * 256 + threadIdx.x;
  if (e >= Cout * Cin * 3) return;
  int co = e / (Cin * 3);
  int r  = e - co * Cin * 3;
  int ci = r / 3;
  int t  = r - ci * 3;
  wt[((size_t)t * Cout + co) * Cin + ci] = f2bf(w[e]);
}

// ---------------- circular conv1d (k=3) as MFMA GEMM ----------------
// Z: bf16 [b][l][ci]; Wt: bf16 [3][Cout][Cin]; out bf16 strided:
// out[b*L*Cout + l*osl + co*osc]. Tile 128(l) x 128(co), 4 waves (2x2 of 64x64),
// BK=64 over ci; one staged A-tile (rows l0-1..l0+128) serves all 3 taps.
__global__ __launch_bounds__(256, 2) void conv_mfma_kernel(
    const u16* __restrict__ Z, const u16* __restrict__ Wt,
    const float* __restrict__ bias, u16* __restrict__ out,
    int L, int Cin, int Cout, int osl, int osc, int relu) {
  __shared__ u16 Zs[130][72];      // rows padded to 72 bf16 (144B) -> conflict-free
  __shared__ u16 Ws[3][128][72];
  int l0 = blockIdx.x * 128, co0 = blockIdx.y * 128, b = blockIdx.z;
  int tid = threadIdx.x;
  int lane = tid & 63, w = tid >> 6, wr = w >> 1, wc = w & 1;
  int row16 = lane & 15, k8 = (lane >> 4) * 8;
  f32x4 acc[4][4];
#pragma unroll
  for (int i = 0; i < 4; ++i)
#pragma unroll
    for (int j = 0; j < 4; ++j) acc[i][j] = (f32x4){0.f, 0.f, 0.f, 0.f};
  const u16* Zb = Z + (size_t)b * L * Cin;
  for (int c0 = 0; c0 < Cin; c0 += 64) {
    for (int e = tid; e < 130 * 8; e += 256) {
      int r = e >> 3, c = e & 7;
      int gl = l0 + r - 1;
      if (gl < 0) gl += L; else if (gl >= L) gl -= L;
      *(uint4*)&Zs[r][c * 8] = *(const uint4*)(Zb + (size_t)gl * Cin + c0 + c * 8);
    }
    for (int e = tid; e < 3 * 128 * 8; e += 256) {
      int t = e >> 10, rem = e & 1023, rw = rem >> 3, c = rem & 7;
      *(uint4*)&Ws[t][rw][c * 8] =
          *(const uint4*)(Wt + ((size_t)t * Cout + co0 + rw) * Cin + c0 + c * 8);
    }
    __syncthreads();
#pragma unroll
    for (int t = 0; t < 3; ++t)
#pragma unroll
      for (int ks = 0; ks < 2; ++ks) {
        int k0 = ks * 32 + k8;
        bf16x8 af[4], bfr[4];
#pragma unroll
        for (int mi = 0; mi < 4; ++mi)
          af[mi] = *(const bf16x8*)&Zs[wr * 64 + mi * 16 + row16 + t][k0];
#pragma unroll
        for (int ni = 0; ni < 4; ++ni)
          bfr[ni] = *(const bf16x8*)&Ws[t][wc * 64 + ni * 16 + row16][k0];
#pragma unroll
        for (int mi = 0; mi < 4; ++mi)
#pragma unroll
          for (int ni = 0; ni < 4; ++ni)
            acc[mi][ni] = __builtin_amdgcn_mfma_f32_16x16x32_bf16(
                af[mi], bfr[ni], acc[mi][ni], 0, 0, 0);
      }
    __syncthreads();
  }
  size_t ob = (size_t)b * L * Cout;
#pragma unroll
  for (int ni = 0; ni < 4; ++ni) {
    int co = co0 + wc * 64 + ni * 16 + row16;
    float bz = bias[co];
#pragma unroll
    for (int mi = 0; mi < 4; ++mi) {
#pragma unroll
      for (int r = 0; r < 4; ++r) {
        int l = l0 + wr * 64 + mi * 16 + (lane >> 4) * 4 + r;
        float v = acc[mi][ni][r] + bz;
        if (relu) v = fmaxf(v, 0.f);
        out[ob + (size_t)l * osl + (size_t)co * osc] = f2bf(v);
      }
    }
  }
}

// ---------------- fused cross attention (unchanged, fp32 vector) ----------------
__global__ __launch_bounds__(256, 2) void attn_kernel(
    const u16* __restrict__ qh, const u16* __restrict__ kh, const u16* __restrict__ vh,
    const u16* __restrict__ ql, const u16* __restrict__ kl, const u16* __restrict__ vl,
    u16* __restrict__ ctx) {
  __shared__ float Qs[32][68];
  __shared__ float KVs[64][68];
  __shared__ u16 Ps[32][520];
  __shared__ float rowsum[32];
  int qt = blockIdx.x, h = blockIdx.y, bz = blockIdx.z;
  int b = bz >> 1, br = bz & 1;
  const u16* Q = br ? ql : qh;
  const u16* K = br ? kh : kl;
  const u16* V = br ? vl : vh;
  size_t base = ((size_t)b * FEA_) * DM_ + h * 64;
  int q0 = qt * 32;
  int tid = threadIdx.x, ty = tid >> 4, tx = tid & 15;
  for (int e = tid; e < 32 * 16; e += 256) {
    int r = e >> 4, q4 = e & 15;
    ushort4 u = *(const ushort4*)(Q + base + (size_t)(q0 + r) * DM_ + q4 * 4);
    float4 f; f.x = bf2f(u.x); f.y = bf2f(u.y); f.z = bf2f(u.z); f.w = bf2f(u.w);
    *(float4*)&Qs[r][q4 * 4] = f;
  }
  float rs[2] = {0.f, 0.f};
  for (int kt = 0; kt < 8; ++kt) {
    __syncthreads();
    for (int e = tid; e < 64 * 16; e += 256) {
      int r = e >> 4, q4 = e & 15;
      ushort4 u = *(const ushort4*)(K + base + (size_t)(kt * 64 + r) * DM_ + q4 * 4);
      float4 f; f.x = bf2f(u.x); f.y = bf2f(u.y); f.z = bf2f(u.z); f.w = bf2f(u.w);
      *(float4*)&KVs[r][q4 * 4] = f;
    }
    __syncthreads();
    float s[2][4] = {{0.f, 0.f, 0.f, 0.f}};
    for (int d = 0; d < 64; d += 4) {
      float4 qv0 = *(float4*)&Qs[ty][d];
      float4 qv1 = *(float4*)&Qs[ty + 16][d];
#pragma unroll
      for (int j = 0; j < 4; ++j) {
        float4 kv = *(float4*)&KVs[tx + 16 * j][d];
        s[0][j] += qv0.x * kv.x + qv0.y * kv.y + qv0.z * kv.z + qv0.w * kv.w;
        s[1][j] += qv1.x * kv.x + qv1.y * kv.y + qv1.z * kv.z + qv1.w * kv.w;
      }
    }
#pragma unroll
    for (int i = 0; i < 2; ++i)
#pragma unroll
      for (int j = 0; j < 4; ++j) {
        float p = __expf(s[i][j] * 0.25f);
        Ps[ty + 16 * i][kt * 64 + tx + 16 * j] = f2bf(p);
        rs[i] += p;
      }
  }
#pragma unroll
  for (int i = 0; i < 2; ++i) {
#pragma unroll
    for (int m = 1; m < 16; m <<= 1) rs[i] += __shfl_xor(rs[i], m);
    if (tx == 0) rowsum[ty + 16 * i] = rs[i];
  }
  float o[2][4] = {{0.f, 0.f, 0.f, 0.f}};
  for (int kt = 0; kt < 8; ++kt) {
    __syncthreads();
    for (int e = tid; e < 64 * 16; e += 256) {
      int r = e >> 4, q4 = e & 15;
      ushort4 u = *(const ushort4*)(V + base + (size_t)(kt * 64 + r) * DM_ + q4 * 4);
      KVs[q4 * 4 + 0][r] = bf2f(u.x);
      KVs[q4 * 4 + 1][r] = bf2f(u.y);
      KVs[q4 * 4 + 2][r] = bf2f(u.z);
      KVs[q4 * 4 + 3][r] = bf2f(u.w);
    }
    __syncthreads();
    for (int kc = 0; kc < 64; kc += 4) {
      ushort4 pu0 = *(const ushort4*)&Ps[ty][kt * 64 + kc];
      ushort4 pu1 = *(const ushort4*)&Ps[ty + 16][kt * 64 + kc];
#pragma unroll
      for (int j = 0; j < 4; ++j) {
        float4 vv = *(float4*)&KVs[tx + 16 * j][kc];
        o[0][j] += bf2f(pu0.x) * vv.x + bf2f(pu0.y) * vv.y + bf2f(pu0.z) * vv.z + bf2f(pu0.w) * vv.w;
        o[1][j] += bf2f(pu1.x) * vv.x + bf2f(pu1.y) * vv.y + bf2f(pu1.z) * vv.z + bf2f(pu1.w) * vv.w;
      }
    }
  }
  __syncthreads();
  float inv0 = 1.0f / rowsum[ty];
  float inv1 = 1.0f / rowsum[ty + 16];
#pragma unroll
  for (int i = 0; i < 2; ++i) {
    float inv = i ? inv1 : inv0;
#pragma unroll
    for (int j = 0; j < 4; ++j) {
      int d = h * 64 + tx + 16 * j;
      int cf = br * 512 + q0 + ty + 16 * i;
      ctx[((size_t)b * DM_ + d) * (2 * FEA_) + cf] = f2bf(o[i][j] * inv);
    }
  }
}

// ---------------- LayerNorm over last axis (+optional f32 residual out) ----------------
template <int RESID>
__global__ void ln_kernel(const u16* __restrict__ in, const float* __restrict__ g,
                          const float* __restrict__ beta, const float* __restrict__ resid,
                          void* __restrict__ outp, int C) {
  int row = blockIdx.x;
  int tid = threadIdx.x;
  const u16* p = in + (size_t)row * C;
  float s = 0.f, ss = 0.f;
  for (int c = tid; c < C; c += 256) {
    float v = bf2f(p[c]);
    s += v; ss += v * v;
  }
#pragma unroll
  for (int m = 1; m < 64; m <<= 1) { s += __shfl_xor(s, m); ss += __shfl_xor(ss, m); }
  __shared__ float red[2][4];
  int wid = tid >> 6, lane = tid & 63;
  if (lane == 0) { red[0][wid] = s; red[1][wid] = ss; }
  __syncthreads();
  s  = red[0][0] + red[0][1] + red[0][2] + red[0][3];
  ss = red[1][0] + red[1][1] + red[1][2] + red[1][3];
  float m  = s / C;
  float var = ss / C - m * m;
  float inv = rsqrtf(var + 1e-5f);
  for (int c = tid; c < C; c += 256) {
    float v = (bf2f(p[c]) - m) * inv * g[c] + beta[c];
    if (RESID) ((float*)outp)[(size_t)row * C + c] = v + resid[(size_t)row * C + c];
    else       ((u16*)outp)[(size_t)row * C + c]   = f2bf(v);
  }
}

extern "C" void kernel_launch(void* const* d_in, const int* in_sizes, int n_in,
                              void* d_out, int out_size, void* d_ws, size_t ws_size,
                              hipStream_t stream) {
  (void)in_sizes; (void)n_in; (void)out_size; (void)ws_size;
  const float* x      = (const float*)d_in[0];
  const float* Wq     = (const float*)d_in[1];
  const float* bq     = (const float*)d_in[2];
  const float* Wk     = (const float*)d_in[3];
  const float* bk     = (const float*)d_in[4];
  const float* Wv     = (const float*)d_in[5];
  const float* bv     = (const float*)d_in[6];
  const float* uns_w  = (const float*)d_in[7];
  const float* uns_b  = (const float*)d_in[8];
  const float* cv_w1  = (const float*)d_in[9];
  const float* cv_b1  = (const float*)d_in[10];
  const float* cv_w2  = (const float*)d_in[11];
  const float* cv_b2  = (const float*)d_in[12];
  const float* cv_g   = (const float*)d_in[13];
  const float* cv_beta= (const float*)d_in[14];
  const float* up_w1  = (const float*)d_in[15];
  const float* up_b1  = (const float*)d_in[16];
  const float* up_w2  = (const float*)d_in[17];
  const float* up_b2  = (const float*)d_in[18];
  const float* up_g   = (const float*)d_in[19];
  const float* up_beta= (const float*)d_in[20];

  // ---- workspace plan (peak 112 MiB of d_ws; d_out doubles as scratch) ----
  char* ws = (char*)d_ws;
  const size_t MB = 1ull << 20;
  u16* x1    = (u16*)(ws + 0);
  u16* x2    = (u16*)(ws + 8 * MB);
  u16* qhb   = (u16*)(ws + 16 * MB);
  u16* khb   = (u16*)(ws + 32 * MB);
  u16* vhb   = (u16*)(ws + 48 * MB);
  u16* qlb   = (u16*)(ws + 64 * MB);
  u16* klb   = (u16*)(ws + 80 * MB);
  u16* vlb   = (u16*)(ws + 96 * MB);
  u16* wt_proj = (u16*)d_out;          // 3.1 MiB used, dead before attn writes ctx
  u16* ctx   = (u16*)d_out;            // 32 MiB, dead before final ln writes d_out
  u16* wt_uns = (u16*)(ws + 0);
  u16* ctx2  = (u16*)(ws + 16 * MB);
  u16* wt_cv1 = (u16*)(ws + 32 * MB);
  u16* h1    = (u16*)(ws + 56 * MB);
  u16* wt_cv2 = (u16*)(ws + 32 * MB);
  u16* h2    = (u16*)(ws + 0);
  u16* ctx3  = (u16*)(ws + 8 * MB);
  u16* wt_up1 = (u16*)(ws + 16 * MB);
  u16* h3    = (u16*)(ws + 32 * MB);
  u16* wt_up2 = (u16*)(ws + 64 * MB);
  u16* h4    = (u16*)(ws + 16 * MB);

  dwt_kernel<<<(B_ * FEA_ * HALF_ + 255) / 256, 256, 0, stream>>>(x, x1, x2, B_ * FEA_ * HALF_);

  auto wtr = [&](const float* w, u16* wt, int Cout, int Cin) {
    wtrans_kernel<<<(Cout * Cin * 3 + 255) / 256, 256, 0, stream>>>(w, wt, Cout, Cin);
  };
  auto conv = [&](const u16* Z, const u16* wt, const float* bias, u16* out, int L,
                  int Cin, int Cout, int osl, int osc, int relu) {
    conv_mfma_kernel<<<dim3(L / 128, Cout / 128, B_), 256, 0, stream>>>(
        Z, wt, bias, out, L, Cin, Cout, osl, osc, relu);
  };

  // projections (shared weights across both DWT branches)
  wtr(Wq, wt_proj, DM_, HALF_);
  conv(x1, wt_proj, bq, qhb, FEA_, HALF_, DM_, DM_, 1, 0);
  conv(x2, wt_proj, bq, qlb, FEA_, HALF_, DM_, DM_, 1, 0);
  wtr(Wk, wt_proj, DM_, HALF_);
  conv(x1, wt_proj, bk, khb, FEA_, HALF_, DM_, DM_, 1, 0);
  conv(x2, wt_proj, bk, klb, FEA_, HALF_, DM_, DM_, 1, 0);
  wtr(Wv, wt_proj, DM_, HALF_);
  conv(x1, wt_proj, bv, vhb, FEA_, HALF_, DM_, DM_, 1, 0);
  conv(x2, wt_proj, bv, vlb, FEA_, HALF_, DM_, DM_, 1, 0);

  attn_kernel<<<dim3(16, 16, 32), 256, 0, stream>>>(qhb, khb, vhb, qlb, klb, vlb, ctx);

  // unsqueeze conv: conv along d axis, channels 2F->F, transposed write -> ctx2[b][f][d]
  wtr(uns_w, wt_uns, FEA_, 2 * FEA_);
  conv(ctx, wt_uns, uns_b, ctx2, DM_, 2 * FEA_, FEA_, 1, DM_, 0);

  // Convlayer: D_MODEL -> D_FF -> HALF (conv along fea axis), then LN
  wtr(cv_w1, wt_cv1, DFF_, DM_);
  conv(ctx2, wt_cv1, cv_b1, h1, FEA_, DM_, DFF_, DFF_, 1, 1);
  wtr(cv_w2, wt_cv2, HALF_, DFF_);
  conv(h1, wt_cv2, cv_b2, h2, FEA_, DFF_, HALF_, HALF_, 1, 0);
  ln_kernel<0><<<B_ * FEA_, 256, 0, stream>>>(h2, cv_g, cv_beta, nullptr, ctx3, HALF_);

  // upsizeConvlayer: HALF -> D_FF -> D_MODEL, then LN + residual
  wtr(up_w1, wt_up1, DFF_, HALF_);
  conv(ctx3, wt_up1, up_b1, h3, FEA_, HALF_, DFF_, DFF_, 1, 1);
  wtr(up_w2, wt_up2, DM_, DFF_);
  conv(h3, wt_up2, up_b2, h4, FEA_, DFF_, DM_, DM_, 1, 0);
  ln_kernel<1><<<B_ * FEA_, 256, 0, stream>>>(h4, up_g, up_beta, x, d_out, DM_);
}

// Round 5
// 1492.020 us; speedup vs baseline: 6.1063x; 1.6247x over previous
//
#include <hip/hip_runtime.h>
#include <hip/hip_bf16.h>

#define B_    16
#define FEA_  512
#define DM_   1024
#define HALF_ 512
#define DFF_  2048

typedef unsigned short u16;
typedef __attribute__((ext_vector_type(8))) short bf16x8;
typedef __attribute__((ext_vector_type(4))) float f32x4;

__device__ __forceinline__ float bf2f(u16 u) {
  union { unsigned int i; float f; } v; v.i = ((unsigned int)u) << 16; return v.f;
}
__device__ __forceinline__ u16 f2bf(float f) {
  union { float f; unsigned int i; } v; v.f = f;
  unsigned int x = v.i;
  return (u16)((x + 0x7fffu + ((x >> 16) & 1u)) >> 16);
}

// ---------------- DWT (Haar, level 1, last axis) ----------------
__global__ void dwt_kernel(const float* __restrict__ x, u16* __restrict__ x1,
                           u16* __restrict__ x2, int n) {
  int i = blockIdx.x * 256 + threadIdx.x;
  if (i >= n) return;
  float2 v = ((const float2*)x)[i];
  x1[i] = f2bf((v.x + v.y) * 0.70710678118f);
  x2[i] = f2bf((v.x - v.y) * 0.70710678118f);
}

// ---------------- weight transpose (Cout,Cin,3) -> bf16 (3,Cout,Cin) ----------------
__global__ void wtrans_kernel(const float* __restrict__ w, u16* __restrict__ wt,
                              int Cout, int Cin) {
  int e = blockIdx.x * 256 + threadIdx.x;
  if (e >= Cout * Cin * 3) return;
  int co = e / (Cin * 3);
  int r  = e - co * Cin * 3;
  int ci = r / 3;
  int t  = r - ci * 3;
  wt[((size_t)t * Cout + co) * Cin + ci] = f2bf(w[e]);
}

// ---------------- circular conv1d (k=3) as MFMA GEMM ----------------
__global__ __launch_bounds__(256, 2) void conv_mfma_kernel(
    const u16* __restrict__ Z, const u16* __restrict__ Wt,
    const float* __restrict__ bias, u16* __restrict__ out,
    int L, int Cin, int Cout, int osl, int osc, int relu) {
  __shared__ u16 Zs[130][72];
  __shared__ u16 Ws[3][128][72];
  int l0 = blockIdx.x * 128, co0 = blockIdx.y * 128, b = blockIdx.z;
  int tid = threadIdx.x;
  int lane = tid & 63, w = tid >> 6, wr = w >> 1, wc = w & 1;
  int row16 = lane & 15, k8 = (lane >> 4) * 8;
  f32x4 acc[4][4];
#pragma unroll
  for (int i = 0; i < 4; ++i)
#pragma unroll
    for (int j = 0; j < 4; ++j) acc[i][j] = (f32x4){0.f, 0.f, 0.f, 0.f};
  const u16* Zb = Z + (size_t)b * L * Cin;
  for (int c0 = 0; c0 < Cin; c0 += 64) {
    for (int e = tid; e < 130 * 8; e += 256) {
      int r = e >> 3, c = e & 7;
      int gl = l0 + r - 1;
      if (gl < 0) gl += L; else if (gl >= L) gl -= L;
      *(uint4*)&Zs[r][c * 8] = *(const uint4*)(Zb + (size_t)gl * Cin + c0 + c * 8);
    }
    for (int e = tid; e < 3 * 128 * 8; e += 256) {
      int t = e >> 10, rem = e & 1023, rw = rem >> 3, c = rem & 7;
      *(uint4*)&Ws[t][rw][c * 8] =
          *(const uint4*)(Wt + ((size_t)t * Cout + co0 + rw) * Cin + c0 + c * 8);
    }
    __syncthreads();
#pragma unroll
    for (int t = 0; t < 3; ++t)
#pragma unroll
      for (int ks = 0; ks < 2; ++ks) {
        int k0 = ks * 32 + k8;
        bf16x8 af[4], bfr[4];
#pragma unroll
        for (int mi = 0; mi < 4; ++mi)
          af[mi] = *(const bf16x8*)&Zs[wr * 64 + mi * 16 + row16 + t][k0];
#pragma unroll
        for (int ni = 0; ni < 4; ++ni)
          bfr[ni] = *(const bf16x8*)&Ws[t][wc * 64 + ni * 16 + row16][k0];
#pragma unroll
        for (int mi = 0; mi < 4; ++mi)
#pragma unroll
          for (int ni = 0; ni < 4; ++ni)
            acc[mi][ni] = __builtin_amdgcn_mfma_f32_16x16x32_bf16(
                af[mi], bfr[ni], acc[mi][ni], 0, 0, 0);
      }
    __syncthreads();
  }
  size_t ob = (size_t)b * L * Cout;
#pragma unroll
  for (int ni = 0; ni < 4; ++ni) {
    int co = co0 + wc * 64 + ni * 16 + row16;
    float bz = bias[co];
#pragma unroll
    for (int mi = 0; mi < 4; ++mi) {
#pragma unroll
      for (int r = 0; r < 4; ++r) {
        int l = l0 + wr * 64 + mi * 16 + (lane >> 4) * 4 + r;
        float v = acc[mi][ni][r] + bz;
        if (relu) v = fmaxf(v, 0.f);
        out[ob + (size_t)l * osl + (size_t)co * osc] = f2bf(v);
      }
    }
  }
}

// ---------------- fused cross attention, MFMA ----------------
// grid: (qtile 8, head 16, b*2+branch 32), block 256 (4 waves, 2x2).
// Q,K: bf16 [b][fea][1024]; Vt: bf16 [b][1024 d][512 fea] (produced transposed).
// Softmax = exp(s*0.25)/rowsum, no max-sub (|s*0.25| <~ 8).
// Output: ctx[b][d][cf], cf = br*512 + q.
__global__ __launch_bounds__(256, 4) void attn_mfma_kernel(
    const u16* __restrict__ qh, const u16* __restrict__ kh, const u16* __restrict__ vhT,
    const u16* __restrict__ ql, const u16* __restrict__ kl, const u16* __restrict__ vlT,
    u16* __restrict__ ctx) {
  __shared__ u16 Qs[64][72], Ks[64][72], Vts[64][72];
  __shared__ u16 Ps[64][72];   // P[q][k] during PV; reused as Ot[d][q] for epilogue
  __shared__ float rsl[2][2][32];  // [wr][wc][q_local] softmax denominator partials
  int qt = blockIdx.x, h = blockIdx.y, bz = blockIdx.z;
  int b = bz >> 1, br = bz & 1;
  const u16* Q  = br ? ql  : qh;
  const u16* K  = br ? kh  : kl;
  const u16* Vt = br ? vlT : vhT;
  int tid = threadIdx.x;
  int lane = tid & 63, w = tid >> 6, wr = w >> 1, wc = w & 1;
  int row16 = lane & 15, g4 = lane >> 4, k8 = g4 * 8;
  int q0 = qt * 64;
  size_t baseQK = (size_t)b * FEA_ * DM_ + h * 64;
  size_t baseV  = (size_t)b * DM_ * FEA_ + (size_t)(h * 64) * FEA_;
  for (int e = tid; e < 64 * 8; e += 256) {
    int r = e >> 3, c = e & 7;
    *(uint4*)&Qs[r][c * 8] = *(const uint4*)(Q + baseQK + (size_t)(q0 + r) * DM_ + c * 8);
  }
  f32x4 oacc[2][2];
  float rsum[2][4];
#pragma unroll
  for (int i = 0; i < 2; ++i) {
#pragma unroll
    for (int j = 0; j < 2; ++j) oacc[i][j] = (f32x4){0.f, 0.f, 0.f, 0.f};
#pragma unroll
    for (int r = 0; r < 4; ++r) rsum[i][r] = 0.f;
  }
  for (int kt = 0; kt < 8; ++kt) {
    __syncthreads();   // prev PV done before restaging K/Vt (also publishes Qs at kt=0)
    for (int e = tid; e < 64 * 8; e += 256) {
      int r = e >> 3, c = e & 7;
      *(uint4*)&Ks[r][c * 8]  = *(const uint4*)(K + baseQK + (size_t)(kt * 64 + r) * DM_ + c * 8);
      *(uint4*)&Vts[r][c * 8] = *(const uint4*)(Vt + baseV + (size_t)r * FEA_ + kt * 64 + c * 8);
    }
    __syncthreads();
    f32x4 sacc[2][2];
#pragma unroll
    for (int i = 0; i < 2; ++i)
#pragma unroll
      for (int j = 0; j < 2; ++j) sacc[i][j] = (f32x4){0.f, 0.f, 0.f, 0.f};
#pragma unroll
    for (int ks = 0; ks < 2; ++ks) {
      int k0 = ks * 32 + k8;
      bf16x8 a0 = *(const bf16x8*)&Qs[wr * 32 + row16][k0];
      bf16x8 a1 = *(const bf16x8*)&Qs[wr * 32 + 16 + row16][k0];
      bf16x8 b0 = *(const bf16x8*)&Ks[wc * 32 + row16][k0];
      bf16x8 b1 = *(const bf16x8*)&Ks[wc * 32 + 16 + row16][k0];
      sacc[0][0] = __builtin_amdgcn_mfma_f32_16x16x32_bf16(a0, b0, sacc[0][0], 0, 0, 0);
      sacc[0][1] = __builtin_amdgcn_mfma_f32_16x16x32_bf16(a0, b1, sacc[0][1], 0, 0, 0);
      sacc[1][0] = __builtin_amdgcn_mfma_f32_16x16x32_bf16(a1, b0, sacc[1][0], 0, 0, 0);
      sacc[1][1] = __builtin_amdgcn_mfma_f32_16x16x32_bf16(a1, b1, sacc[1][1], 0, 0, 0);
    }
#pragma unroll
    for (int mi = 0; mi < 2; ++mi)
#pragma unroll
      for (int ni = 0; ni < 2; ++ni)
#pragma unroll
        for (int r = 0; r < 4; ++r) {
          float p = __expf(sacc[mi][ni][r] * 0.25f);
          rsum[mi][r] += p;
          Ps[wr * 32 + mi * 16 + g4 * 4 + r][wc * 32 + ni * 16 + row16] = f2bf(p);
        }
    __syncthreads();
#pragma unroll
    for (int ks = 0; ks < 2; ++ks) {
      int k0 = ks * 32 + k8;
      bf16x8 a0 = *(const bf16x8*)&Ps[wr * 32 + row16][k0];
      bf16x8 a1 = *(const bf16x8*)&Ps[wr * 32 + 16 + row16][k0];
      bf16x8 b0 = *(const bf16x8*)&Vts[wc * 32 + row16][k0];
      bf16x8 b1 = *(const bf16x8*)&Vts[wc * 32 + 16 + row16][k0];
      oacc[0][0] = __builtin_amdgcn_mfma_f32_16x16x32_bf16(a0, b0, oacc[0][0], 0, 0, 0);
      oacc[0][1] = __builtin_amdgcn_mfma_f32_16x16x32_bf16(a0, b1, oacc[0][1], 0, 0, 0);
      oacc[1][0] = __builtin_amdgcn_mfma_f32_16x16x32_bf16(a1, b0, oacc[1][0], 0, 0, 0);
      oacc[1][1] = __builtin_amdgcn_mfma_f32_16x16x32_bf16(a1, b1, oacc[1][1], 0, 0, 0);
    }
  }
  // ---- softmax denominator: 16-lane butterfly, then cross-wave (wc) exchange ----
#pragma unroll
  for (int mi = 0; mi < 2; ++mi)
#pragma unroll
    for (int r = 0; r < 4; ++r) {
#pragma unroll
      for (int m = 1; m < 16; m <<= 1) rsum[mi][r] += __shfl_xor(rsum[mi][r], m);
    }
  if (row16 == 0) {
#pragma unroll
    for (int mi = 0; mi < 2; ++mi)
#pragma unroll
      for (int r = 0; r < 4; ++r) rsl[wr][wc][mi * 16 + g4 * 4 + r] = rsum[mi][r];
  }
  __syncthreads();   // publishes rsl; also: last PV reads of Ps done -> reuse as Ot[d][q]
#pragma unroll
  for (int mi = 0; mi < 2; ++mi)
#pragma unroll
    for (int ni = 0; ni < 2; ++ni)
#pragma unroll
      for (int r = 0; r < 4; ++r) {
        int qq = mi * 16 + g4 * 4 + r;
        float denom = rsl[wr][0][qq] + rsl[wr][1][qq];
        float o = oacc[mi][ni][r] / denom;
        Ps[wc * 32 + ni * 16 + row16][wr * 32 + qq] = f2bf(o);
      }
  __syncthreads();
  for (int e = tid; e < 64 * 8; e += 256) {
    int r = e >> 3, c = e & 7;   // r = local d, c*8 = q chunk
    size_t dst = ((size_t)b * DM_ + h * 64 + r) * (2 * FEA_) + br * 512 + q0 + c * 8;
    *(uint4*)(ctx + dst) = *(const uint4*)&Ps[r][c * 8];
  }
}

// ---------------- LayerNorm over last axis (+optional f32 residual out) ----------------
template <int RESID>
__global__ void ln_kernel(const u16* __restrict__ in, const float* __restrict__ g,
                          const float* __restrict__ beta, const float* __restrict__ resid,
                          void* __restrict__ outp, int C) {
  int row = blockIdx.x;
  int tid = threadIdx.x;
  const u16* p = in + (size_t)row * C;
  float s = 0.f, ss = 0.f;
  for (int c = tid; c < C; c += 256) {
    float v = bf2f(p[c]);
    s += v; ss += v * v;
  }
#pragma unroll
  for (int m = 1; m < 64; m <<= 1) { s += __shfl_xor(s, m); ss += __shfl_xor(ss, m); }
  __shared__ float red[2][4];
  int wid = tid >> 6, lane = tid & 63;
  if (lane == 0) { red[0][wid] = s; red[1][wid] = ss; }
  __syncthreads();
  s  = red[0][0] + red[0][1] + red[0][2] + red[0][3];
  ss = red[1][0] + red[1][1] + red[1][2] + red[1][3];
  float m  = s / C;
  float var = ss / C - m * m;
  float inv = rsqrtf(var + 1e-5f);
  for (int c = tid; c < C; c += 256) {
    float v = (bf2f(p[c]) - m) * inv * g[c] + beta[c];
    if (RESID) ((float*)outp)[(size_t)row * C + c] = v + resid[(size_t)row * C + c];
    else       ((u16*)outp)[(size_t)row * C + c]   = f2bf(v);
  }
}

extern "C" void kernel_launch(void* const* d_in, const int* in_sizes, int n_in,
                              void* d_out, int out_size, void* d_ws, size_t ws_size,
                              hipStream_t stream) {
  (void)in_sizes; (void)n_in; (void)out_size; (void)ws_size;
  const float* x      = (const float*)d_in[0];
  const float* Wq     = (const float*)d_in[1];
  const float* bq     = (const float*)d_in[2];
  const float* Wk     = (const float*)d_in[3];
  const float* bk     = (const float*)d_in[4];
  const float* Wv     = (const float*)d_in[5];
  const float* bv     = (const float*)d_in[6];
  const float* uns_w  = (const float*)d_in[7];
  const float* uns_b  = (const float*)d_in[8];
  const float* cv_w1  = (const float*)d_in[9];
  const float* cv_b1  = (const float*)d_in[10];
  const float* cv_w2  = (const float*)d_in[11];
  const float* cv_b2  = (const float*)d_in[12];
  const float* cv_g   = (const float*)d_in[13];
  const float* cv_beta= (const float*)d_in[14];
  const float* up_w1  = (const float*)d_in[15];
  const float* up_b1  = (const float*)d_in[16];
  const float* up_w2  = (const float*)d_in[17];
  const float* up_b2  = (const float*)d_in[18];
  const float* up_g   = (const float*)d_in[19];
  const float* up_beta= (const float*)d_in[20];

  // ---- workspace plan (peak 112 MiB of d_ws; d_out doubles as scratch) ----
  char* ws = (char*)d_ws;
  const size_t MB = 1ull << 20;
  u16* x1    = (u16*)(ws + 0);
  u16* x2    = (u16*)(ws + 8 * MB);
  u16* qhb   = (u16*)(ws + 16 * MB);
  u16* khb   = (u16*)(ws + 32 * MB);
  u16* vhb   = (u16*)(ws + 48 * MB);   // stored TRANSPOSED: [b][d][fea]
  u16* qlb   = (u16*)(ws + 64 * MB);
  u16* klb   = (u16*)(ws + 80 * MB);
  u16* vlb   = (u16*)(ws + 96 * MB);   // stored TRANSPOSED: [b][d][fea]
  u16* wt_proj = (u16*)d_out;
  u16* ctx   = (u16*)d_out;
  u16* wt_uns = (u16*)(ws + 0);
  u16* ctx2  = (u16*)(ws + 16 * MB);
  u16* wt_cv1 = (u16*)(ws + 32 * MB);
  u16* h1    = (u16*)(ws + 56 * MB);
  u16* wt_cv2 = (u16*)(ws + 32 * MB);
  u16* h2    = (u16*)(ws + 0);
  u16* ctx3  = (u16*)(ws + 8 * MB);
  u16* wt_up1 = (u16*)(ws + 16 * MB);
  u16* h3    = (u16*)(ws + 32 * MB);
  u16* wt_up2 = (u16*)(ws + 64 * MB);
  u16* h4    = (u16*)(ws + 16 * MB);

  dwt_kernel<<<(B_ * FEA_ * HALF_ + 255) / 256, 256, 0, stream>>>(x, x1, x2, B_ * FEA_ * HALF_);

  auto wtr = [&](const float* w, u16* wt, int Cout, int Cin) {
    wtrans_kernel<<<(Cout * Cin * 3 + 255) / 256, 256, 0, stream>>>(w, wt, Cout, Cin);
  };
  auto conv = [&](const u16* Z, const u16* wt, const float* bias, u16* out, int L,
                  int Cin, int Cout, int osl, int osc, int relu) {
    conv_mfma_kernel<<<dim3(L / 128, Cout / 128, B_), 256, 0, stream>>>(
        Z, wt, bias, out, L, Cin, Cout, osl, osc, relu);
  };

  // projections (shared weights across both DWT branches); V written transposed
  wtr(Wq, wt_proj, DM_, HALF_);
  conv(x1, wt_proj, bq, qhb, FEA_, HALF_, DM_, DM_, 1, 0);
  conv(x2, wt_proj, bq, qlb, FEA_, HALF_, DM_, DM_, 1, 0);
  wtr(Wk, wt_proj, DM_, HALF_);
  conv(x1, wt_proj, bk, khb, FEA_, HALF_, DM_, DM_, 1, 0);
  conv(x2, wt_proj, bk, klb, FEA_, HALF_, DM_, DM_, 1, 0);
  wtr(Wv, wt_proj, DM_, HALF_);
  conv(x1, wt_proj, bv, vhb, FEA_, HALF_, DM_, 1, FEA_, 0);
  conv(x2, wt_proj, bv, vlb, FEA_, HALF_, DM_, 1, FEA_, 0);

  attn_mfma_kernel<<<dim3(8, 16, 32), 256, 0, stream>>>(qhb, khb, vhb, qlb, klb, vlb, ctx);

  // unsqueeze conv: conv along d axis, channels 2F->F, transposed write -> ctx2[b][f][d]
  wtr(uns_w, wt_uns, FEA_, 2 * FEA_);
  conv(ctx, wt_uns, uns_b, ctx2, DM_, 2 * FEA_, FEA_, 1, DM_, 0);

  // Convlayer: D_MODEL -> D_FF -> HALF (conv along fea axis), then LN
  wtr(cv_w1, wt_cv1, DFF_, DM_);
  conv(ctx2, wt_cv1, cv_b1, h1, FEA_, DM_, DFF_, DFF_, 1, 1);
  wtr(cv_w2, wt_cv2, HALF_, DFF_);
  conv(h1, wt_cv2, cv_b2, h2, FEA_, DFF_, HALF_, HALF_, 1, 0);
  ln_kernel<0><<<B_ * FEA_, 256, 0, stream>>>(h2, cv_g, cv_beta, nullptr, ctx3, HALF_);

  // upsizeConvlayer: HALF -> D_FF -> D_MODEL, then LN + residual
  wtr(up_w1, wt_up1, DFF_, HALF_);
  conv(ctx3, wt_up1, up_b1, h3, FEA_, HALF_, DFF_, DFF_, 1, 1);
  wtr(up_w2, wt_up2, DM_, DFF_);
  conv(h3, wt_up2, up_b2, h4, FEA_, DFF_, DM_, DM_, 1, 0);
  ln_kernel<1><<<B_ * FEA_, 256, 0, stream>>>(h4, up_g, up_beta, x, d_out, DM_);
}

// Round 6
// 1437.483 us; speedup vs baseline: 6.3379x; 1.0379x over previous
//
#include <hip/hip_runtime.h>
#include <hip/hip_bf16.h>

#define B_    16
#define FEA_  512
#define DM_   1024
#define HALF_ 512
#define DFF_  2048

typedef unsigned short u16;
typedef __attribute__((ext_vector_type(8))) short bf16x8;
typedef __attribute__((ext_vector_type(4))) float f32x4;

__device__ __forceinline__ float bf2f(u16 u) {
  union { unsigned int i; float f; } v; v.i = ((unsigned int)u) << 16; return v.f;
}
__device__ __forceinline__ u16 f2bf(float f) {
  union { float f; unsigned int i; } v; v.f = f;
  unsigned int x = v.i;
  return (u16)((x + 0x7fffu + ((x >> 16) & 1u)) >> 16);
}

// ---------------- DWT (Haar, level 1, last axis) ----------------
__global__ void dwt_kernel(const float* __restrict__ x, u16* __restrict__ x1,
                           u16* __restrict__ x2, int n) {
  int i = blockIdx.x * 256 + threadIdx.x;
  if (i >= n) return;
  float2 v = ((const float2*)x)[i];
  x1[i] = f2bf((v.x + v.y) * 0.70710678118f);
  x2[i] = f2bf((v.x - v.y) * 0.70710678118f);
}

// ---------------- weight transpose (Cout,Cin,3) -> bf16 (3,Cout,Cin) ----------------
__global__ void wtrans_kernel(const float* __restrict__ w, u16* __restrict__ wt,
                              int Cout, int Cin) {
  int e = blockIdx.x * 256 + threadIdx.x;
  if (e >= Cout * Cin * 3) return;
  int co = e / (Cin * 3);
  int r  = e - co * Cin * 3;
  int ci = r / 3;
  int t  = r - ci * 3;
  wt[((size_t)t * Cout + co) * Cin + ci] = f2bf(w[e]);
}

// ---------------- circular conv1d (k=3) as MFMA GEMM ----------------
// LDS rows = 64 u16 (128 B, 8 x 16B slots), XOR slot swizzle slot^=(row&7)
// on BOTH staging writes and fragment reads -> conflict-free b128 access.
__global__ __launch_bounds__(256, 2) void conv_mfma_kernel(
    const u16* __restrict__ Z, const u16* __restrict__ Wt,
    const float* __restrict__ bias, u16* __restrict__ out,
    int L, int Cin, int Cout, int osl, int osc, int relu) {
  __shared__ u16 Zs[130][64];
  __shared__ u16 Ws[3][128][64];
  int l0 = blockIdx.x * 128, co0 = blockIdx.y * 128, b = blockIdx.z;
  int tid = threadIdx.x;
  int lane = tid & 63, w = tid >> 6, wr = w >> 1, wc = w & 1;
  int row16 = lane & 15, g4 = lane >> 4;
  f32x4 acc[4][4];
#pragma unroll
  for (int i = 0; i < 4; ++i)
#pragma unroll
    for (int j = 0; j < 4; ++j) acc[i][j] = (f32x4){0.f, 0.f, 0.f, 0.f};
  const u16* Zb = Z + (size_t)b * L * Cin;
  for (int c0 = 0; c0 < Cin; c0 += 64) {
    for (int e = tid; e < 130 * 8; e += 256) {
      int r = e >> 3, c = e & 7;
      int gl = l0 + r - 1;
      if (gl < 0) gl += L; else if (gl >= L) gl -= L;
      *(uint4*)&Zs[r][(c ^ (r & 7)) * 8] =
          *(const uint4*)(Zb + (size_t)gl * Cin + c0 + c * 8);
    }
    for (int e = tid; e < 3 * 128 * 8; e += 256) {
      int t = e >> 10, rem = e & 1023, rw = rem >> 3, c = rem & 7;
      *(uint4*)&Ws[t][rw][(c ^ (rw & 7)) * 8] =
          *(const uint4*)(Wt + ((size_t)t * Cout + co0 + rw) * Cin + c0 + c * 8);
    }
    __syncthreads();
#pragma unroll
    for (int t = 0; t < 3; ++t)
#pragma unroll
      for (int ks = 0; ks < 2; ++ks) {
        int s = ks * 4 + g4;   // 16B slot index within row
        bf16x8 af[4], bfr[4];
#pragma unroll
        for (int mi = 0; mi < 4; ++mi) {
          int ra = wr * 64 + mi * 16 + row16 + t;
          af[mi] = *(const bf16x8*)&Zs[ra][(s ^ (ra & 7)) * 8];
        }
#pragma unroll
        for (int ni = 0; ni < 4; ++ni) {
          int rb = wc * 64 + ni * 16 + row16;
          bfr[ni] = *(const bf16x8*)&Ws[t][rb][(s ^ (rb & 7)) * 8];
        }
#pragma unroll
        for (int mi = 0; mi < 4; ++mi)
#pragma unroll
          for (int ni = 0; ni < 4; ++ni)
            acc[mi][ni] = __builtin_amdgcn_mfma_f32_16x16x32_bf16(
                af[mi], bfr[ni], acc[mi][ni], 0, 0, 0);
      }
    __syncthreads();
  }
  size_t ob = (size_t)b * L * Cout;
#pragma unroll
  for (int ni = 0; ni < 4; ++ni) {
    int co = co0 + wc * 64 + ni * 16 + row16;
    float bz = bias[co];
#pragma unroll
    for (int mi = 0; mi < 4; ++mi) {
#pragma unroll
      for (int r = 0; r < 4; ++r) {
        int l = l0 + wr * 64 + mi * 16 + g4 * 4 + r;
        float v = acc[mi][ni][r] + bz;
        if (relu) v = fmaxf(v, 0.f);
        out[ob + (size_t)l * osl + (size_t)co * osc] = f2bf(v);
      }
    }
  }
}

// ---------------- fused cross attention, MFMA (unchanged from round 5) ----------------
__global__ __launch_bounds__(256, 4) void attn_mfma_kernel(
    const u16* __restrict__ qh, const u16* __restrict__ kh, const u16* __restrict__ vhT,
    const u16* __restrict__ ql, const u16* __restrict__ kl, const u16* __restrict__ vlT,
    u16* __restrict__ ctx) {
  __shared__ u16 Qs[64][72], Ks[64][72], Vts[64][72];
  __shared__ u16 Ps[64][72];   // P[q][k] during PV; reused as Ot[d][q] for epilogue
  __shared__ float rsl[2][2][32];  // [wr][wc][q_local] softmax denominator partials
  int qt = blockIdx.x, h = blockIdx.y, bz = blockIdx.z;
  int b = bz >> 1, br = bz & 1;
  const u16* Q  = br ? ql  : qh;
  const u16* K  = br ? kh  : kl;
  const u16* Vt = br ? vlT : vhT;
  int tid = threadIdx.x;
  int lane = tid & 63, w = tid >> 6, wr = w >> 1, wc = w & 1;
  int row16 = lane & 15, g4 = lane >> 4, k8 = g4 * 8;
  int q0 = qt * 64;
  size_t baseQK = (size_t)b * FEA_ * DM_ + h * 64;
  size_t baseV  = (size_t)b * DM_ * FEA_ + (size_t)(h * 64) * FEA_;
  for (int e = tid; e < 64 * 8; e += 256) {
    int r = e >> 3, c = e & 7;
    *(uint4*)&Qs[r][c * 8] = *(const uint4*)(Q + baseQK + (size_t)(q0 + r) * DM_ + c * 8);
  }
  f32x4 oacc[2][2];
  float rsum[2][4];
#pragma unroll
  for (int i = 0; i < 2; ++i) {
#pragma unroll
    for (int j = 0; j < 2; ++j) oacc[i][j] = (f32x4){0.f, 0.f, 0.f, 0.f};
#pragma unroll
    for (int r = 0; r < 4; ++r) rsum[i][r] = 0.f;
  }
  for (int kt = 0; kt < 8; ++kt) {
    __syncthreads();   // prev PV done before restaging K/Vt (also publishes Qs at kt=0)
    for (int e = tid; e < 64 * 8; e += 256) {
      int r = e >> 3, c = e & 7;
      *(uint4*)&Ks[r][c * 8]  = *(const uint4*)(K + baseQK + (size_t)(kt * 64 + r) * DM_ + c * 8);
      *(uint4*)&Vts[r][c * 8] = *(const uint4*)(Vt + baseV + (size_t)r * FEA_ + kt * 64 + c * 8);
    }
    __syncthreads();
    f32x4 sacc[2][2];
#pragma unroll
    for (int i = 0; i < 2; ++i)
#pragma unroll
      for (int j = 0; j < 2; ++j) sacc[i][j] = (f32x4){0.f, 0.f, 0.f, 0.f};
#pragma unroll
    for (int ks = 0; ks < 2; ++ks) {
      int k0 = ks * 32 + k8;
      bf16x8 a0 = *(const bf16x8*)&Qs[wr * 32 + row16][k0];
      bf16x8 a1 = *(const bf16x8*)&Qs[wr * 32 + 16 + row16][k0];
      bf16x8 b0 = *(const bf16x8*)&Ks[wc * 32 + row16][k0];
      bf16x8 b1 = *(const bf16x8*)&Ks[wc * 32 + 16 + row16][k0];
      sacc[0][0] = __builtin_amdgcn_mfma_f32_16x16x32_bf16(a0, b0, sacc[0][0], 0, 0, 0);
      sacc[0][1] = __builtin_amdgcn_mfma_f32_16x16x32_bf16(a0, b1, sacc[0][1], 0, 0, 0);
      sacc[1][0] = __builtin_amdgcn_mfma_f32_16x16x32_bf16(a1, b0, sacc[1][0], 0, 0, 0);
      sacc[1][1] = __builtin_amdgcn_mfma_f32_16x16x32_bf16(a1, b1, sacc[1][1], 0, 0, 0);
    }
#pragma unroll
    for (int mi = 0; mi < 2; ++mi)
#pragma unroll
      for (int ni = 0; ni < 2; ++ni)
#pragma unroll
        for (int r = 0; r < 4; ++r) {
          float p = __expf(sacc[mi][ni][r] * 0.25f);
          rsum[mi][r] += p;
          Ps[wr * 32 + mi * 16 + g4 * 4 + r][wc * 32 + ni * 16 + row16] = f2bf(p);
        }
    __syncthreads();
#pragma unroll
    for (int ks = 0; ks < 2; ++ks) {
      int k0 = ks * 32 + k8;
      bf16x8 a0 = *(const bf16x8*)&Ps[wr * 32 + row16][k0];
      bf16x8 a1 = *(const bf16x8*)&Ps[wr * 32 + 16 + row16][k0];
      bf16x8 b0 = *(const bf16x8*)&Vts[wc * 32 + row16][k0];
      bf16x8 b1 = *(const bf16x8*)&Vts[wc * 32 + 16 + row16][k0];
      oacc[0][0] = __builtin_amdgcn_mfma_f32_16x16x32_bf16(a0, b0, oacc[0][0], 0, 0, 0);
      oacc[0][1] = __builtin_amdgcn_mfma_f32_16x16x32_bf16(a0, b1, oacc[0][1], 0, 0, 0);
      oacc[1][0] = __builtin_amdgcn_mfma_f32_16x16x32_bf16(a1, b0, oacc[1][0], 0, 0, 0);
      oacc[1][1] = __builtin_amdgcn_mfma_f32_16x16x32_bf16(a1, b1, oacc[1][1], 0, 0, 0);
    }
  }
  // ---- softmax denominator: 16-lane butterfly, then cross-wave (wc) exchange ----
#pragma unroll
  for (int mi = 0; mi < 2; ++mi)
#pragma unroll
    for (int r = 0; r < 4; ++r) {
#pragma unroll
      for (int m = 1; m < 16; m <<= 1) rsum[mi][r] += __shfl_xor(rsum[mi][r], m);
    }
  if (row16 == 0) {
#pragma unroll
    for (int mi = 0; mi < 2; ++mi)
#pragma unroll
      for (int r = 0; r < 4; ++r) rsl[wr][wc][mi * 16 + g4 * 4 + r] = rsum[mi][r];
  }
  __syncthreads();   // publishes rsl; also: last PV reads of Ps done -> reuse as Ot[d][q]
#pragma unroll
  for (int mi = 0; mi < 2; ++mi)
#pragma unroll
    for (int ni = 0; ni < 2; ++ni)
#pragma unroll
      for (int r = 0; r < 4; ++r) {
        int qq = mi * 16 + g4 * 4 + r;
        float denom = rsl[wr][0][qq] + rsl[wr][1][qq];
        float o = oacc[mi][ni][r] / denom;
        Ps[wc * 32 + ni * 16 + row16][wr * 32 + qq] = f2bf(o);
      }
  __syncthreads();
  for (int e = tid; e < 64 * 8; e += 256) {
    int r = e >> 3, c = e & 7;   // r = local d, c*8 = q chunk
    size_t dst = ((size_t)b * DM_ + h * 64 + r) * (2 * FEA_) + br * 512 + q0 + c * 8;
    *(uint4*)(ctx + dst) = *(const uint4*)&Ps[r][c * 8];
  }
}

// ---------------- LayerNorm over last axis (+optional f32 residual out) ----------------
template <int RESID>
__global__ void ln_kernel(const u16* __restrict__ in, const float* __restrict__ g,
                          const float* __restrict__ beta, const float* __restrict__ resid,
                          void* __restrict__ outp, int C) {
  int row = blockIdx.x;
  int tid = threadIdx.x;
  const u16* p = in + (size_t)row * C;
  float s = 0.f, ss = 0.f;
  for (int c = tid; c < C; c += 256) {
    float v = bf2f(p[c]);
    s += v; ss += v * v;
  }
#pragma unroll
  for (int m = 1; m < 64; m <<= 1) { s += __shfl_xor(s, m); ss += __shfl_xor(ss, m); }
  __shared__ float red[2][4];
  int wid = tid >> 6, lane = tid & 63;
  if (lane == 0) { red[0][wid] = s; red[1][wid] = ss; }
  __syncthreads();
  s  = red[0][0] + red[0][1] + red[0][2] + red[0][3];
  ss = red[1][0] + red[1][1] + red[1][2] + red[1][3];
  float m  = s / C;
  float var = ss / C - m * m;
  float inv = rsqrtf(var + 1e-5f);
  for (int c = tid; c < C; c += 256) {
    float v = (bf2f(p[c]) - m) * inv * g[c] + beta[c];
    if (RESID) ((float*)outp)[(size_t)row * C + c] = v + resid[(size_t)row * C + c];
    else       ((u16*)outp)[(size_t)row * C + c]   = f2bf(v);
  }
}

extern "C" void kernel_launch(void* const* d_in, const int* in_sizes, int n_in,
                              void* d_out, int out_size, void* d_ws, size_t ws_size,
                              hipStream_t stream) {
  (void)in_sizes; (void)n_in; (void)out_size; (void)ws_size;
  const float* x      = (const float*)d_in[0];
  const float* Wq     = (const float*)d_in[1];
  const float* bq     = (const float*)d_in[2];
  const float* Wk     = (const float*)d_in[3];
  const float* bk     = (const float*)d_in[4];
  const float* Wv     = (const float*)d_in[5];
  const float* bv     = (const float*)d_in[6];
  const float* uns_w  = (const float*)d_in[7];
  const float* uns_b  = (const float*)d_in[8];
  const float* cv_w1  = (const float*)d_in[9];
  const float* cv_b1  = (const float*)d_in[10];
  const float* cv_w2  = (const float*)d_in[11];
  const float* cv_b2  = (const float*)d_in[12];
  const float* cv_g   = (const float*)d_in[13];
  const float* cv_beta= (const float*)d_in[14];
  const float* up_w1  = (const float*)d_in[15];
  const float* up_b1  = (const float*)d_in[16];
  const float* up_w2  = (const float*)d_in[17];
  const float* up_b2  = (const float*)d_in[18];
  const float* up_g   = (const float*)d_in[19];
  const float* up_beta= (const float*)d_in[20];

  // ---- workspace plan (peak 112 MiB of d_ws; d_out doubles as scratch) ----
  char* ws = (char*)d_ws;
  const size_t MB = 1ull << 20;
  u16* x1    = (u16*)(ws + 0);
  u16* x2    = (u16*)(ws + 8 * MB);
  u16* qhb   = (u16*)(ws + 16 * MB);
  u16* khb   = (u16*)(ws + 32 * MB);
  u16* vhb   = (u16*)(ws + 48 * MB);   // stored TRANSPOSED: [b][d][fea]
  u16* qlb   = (u16*)(ws + 64 * MB);
  u16* klb   = (u16*)(ws + 80 * MB);
  u16* vlb   = (u16*)(ws + 96 * MB);   // stored TRANSPOSED: [b][d][fea]
  u16* wt_proj = (u16*)d_out;
  u16* ctx   = (u16*)d_out;
  u16* wt_uns = (u16*)(ws + 0);
  u16* ctx2  = (u16*)(ws + 16 * MB);
  u16* wt_cv1 = (u16*)(ws + 32 * MB);
  u16* h1    = (u16*)(ws + 56 * MB);
  u16* wt_cv2 = (u16*)(ws + 32 * MB);
  u16* h2    = (u16*)(ws + 0);
  u16* ctx3  = (u16*)(ws + 8 * MB);
  u16* wt_up1 = (u16*)(ws + 16 * MB);
  u16* h3    = (u16*)(ws + 32 * MB);
  u16* wt_up2 = (u16*)(ws + 64 * MB);
  u16* h4    = (u16*)(ws + 16 * MB);

  dwt_kernel<<<(B_ * FEA_ * HALF_ + 255) / 256, 256, 0, stream>>>(x, x1, x2, B_ * FEA_ * HALF_);

  auto wtr = [&](const float* w, u16* wt, int Cout, int Cin) {
    wtrans_kernel<<<(Cout * Cin * 3 + 255) / 256, 256, 0, stream>>>(w, wt, Cout, Cin);
  };
  auto conv = [&](const u16* Z, const u16* wt, const float* bias, u16* out, int L,
                  int Cin, int Cout, int osl, int osc, int relu) {
    conv_mfma_kernel<<<dim3(L / 128, Cout / 128, B_), 256, 0, stream>>>(
        Z, wt, bias, out, L, Cin, Cout, osl, osc, relu);
  };

  // projections (shared weights across both DWT branches); V written transposed
  wtr(Wq, wt_proj, DM_, HALF_);
  conv(x1, wt_proj, bq, qhb, FEA_, HALF_, DM_, DM_, 1, 0);
  conv(x2, wt_proj, bq, qlb, FEA_, HALF_, DM_, DM_, 1, 0);
  wtr(Wk, wt_proj, DM_, HALF_);
  conv(x1, wt_proj, bk, khb, FEA_, HALF_, DM_, DM_, 1, 0);
  conv(x2, wt_proj, bk, klb, FEA_, HALF_, DM_, DM_, 1, 0);
  wtr(Wv, wt_proj, DM_, HALF_);
  conv(x1, wt_proj, bv, vhb, FEA_, HALF_, DM_, 1, FEA_, 0);
  conv(x2, wt_proj, bv, vlb, FEA_, HALF_, DM_, 1, FEA_, 0);

  attn_mfma_kernel<<<dim3(8, 16, 32), 256, 0, stream>>>(qhb, khb, vhb, qlb, klb, vlb, ctx);

  // unsqueeze conv: conv along d axis, channels 2F->F, transposed write -> ctx2[b][f][d]
  wtr(uns_w, wt_uns, FEA_, 2 * FEA_);
  conv(ctx, wt_uns, uns_b, ctx2, DM_, 2 * FEA_, FEA_, 1, DM_, 0);

  // Convlayer: D_MODEL -> D_FF -> HALF (conv along fea axis), then LN
  wtr(cv_w1, wt_cv1, DFF_, DM_);
  conv(ctx2, wt_cv1, cv_b1, h1, FEA_, DM_, DFF_, DFF_, 1, 1);
  wtr(cv_w2, wt_cv2, HALF_, DFF_);
  conv(h1, wt_cv2, cv_b2, h2, FEA_, DFF_, HALF_, HALF_, 1, 0);
  ln_kernel<0><<<B_ * FEA_, 256, 0, stream>>>(h2, cv_g, cv_beta, nullptr, ctx3, HALF_);

  // upsizeConvlayer: HALF -> D_FF -> D_MODEL, then LN + residual
  wtr(up_w1, wt_up1, DFF_, HALF_);
  conv(ctx3, wt_up1, up_b1, h3, FEA_, HALF_, DFF_, DFF_, 1, 1);
  wtr(up_w2, wt_up2, DM_, DFF_);
  conv(h3, wt_up2, up_b2, h4, FEA_, DFF_, DM_, DM_, 1, 0);
  ln_kernel<1><<<B_ * FEA_, 256, 0, stream>>>(h4, up_g, up_beta, x, d_out, DM_);
}

// Round 7
// 1182.409 us; speedup vs baseline: 7.7052x; 1.2157x over previous
//
#include <hip/hip_runtime.h>
#include <hip/hip_bf16.h>

#define B_    16
#define FEA_  512
#define DM_   1024
#define HALF_ 512
#define DFF_  2048

typedef unsigned short u16;
typedef __attribute__((ext_vector_type(8))) short bf16x8;
typedef __attribute__((ext_vector_type(4))) float f32x4;

__device__ __forceinline__ float bf2f(u16 u) {
  union { unsigned int i; float f; } v; v.i = ((unsigned int)u) << 16; return v.f;
}
__device__ __forceinline__ u16 f2bf(float f) {
  union { float f; unsigned int i; } v; v.f = f;
  unsigned int x = v.i;
  return (u16)((x + 0x7fffu + ((x >> 16) & 1u)) >> 16);
}
__device__ __forceinline__ void gload16(const u16* g, u16* l) {
  __builtin_amdgcn_global_load_lds(
      (const __attribute__((address_space(1))) void*)g,
      (__attribute__((address_space(3))) void*)l, 16, 0, 0);
}

// ---------------- DWT (Haar, level 1, last axis) ----------------
__global__ void dwt_kernel(const float* __restrict__ x, u16* __restrict__ x1,
                           u16* __restrict__ x2, int n) {
  int i = blockIdx.x * 256 + threadIdx.x;
  if (i >= n) return;
  float2 v = ((const float2*)x)[i];
  x1[i] = f2bf((v.x + v.y) * 0.70710678118f);
  x2[i] = f2bf((v.x - v.y) * 0.70710678118f);
}

// ---------------- weight transpose (Cout,Cin,3) -> bf16 (3,Cout,Cin) ----------------
__global__ void wtrans_kernel(const float* __restrict__ w, u16* __restrict__ wt,
                              int Cout, int Cin) {
  int e = blockIdx.x * 256 + threadIdx.x;
  if (e >= Cout * Cin * 3) return;
  int co = e / (Cin * 3);
  int r  = e - co * Cin * 3;
  int ci = r / 3;
  int t  = r - ci * 3;
  wt[((size_t)t * Cout + co) * Cin + ci] = f2bf(w[e]);
}

// ---------------- circular conv1d (k=3) as MFMA GEMM ----------------
// Chunked K-loop: chunk = (ci-group of 64, tap). Ws double-buffered via
// global_load_lds (linear LDS dest, XOR swizzle applied on the per-lane GLOBAL
// source; reads use the same XOR). Zs reg-staged (circular halo), swizzled,
// issue-early/write-late at ci-group boundaries. 3 blocks/CU.
__global__ __launch_bounds__(256, 3) void conv_mfma_kernel(
    const u16* __restrict__ Z, const u16* __restrict__ Wt,
    const float* __restrict__ bias, u16* __restrict__ out,
    int L, int Cin, int Cout, int osl, int osc, int relu) {
  __shared__ u16 Zs[130][64];
  __shared__ u16 Wb[2][128][64];
  int l0 = blockIdx.x * 128, co0 = blockIdx.y * 128, b = blockIdx.z;
  int tid = threadIdx.x;
  int lane = tid & 63, w = tid >> 6, wr = w >> 1, wc = w & 1;
  int row16 = lane & 15, g4 = lane >> 4;
  f32x4 acc[4][4];
#pragma unroll
  for (int i = 0; i < 4; ++i)
#pragma unroll
    for (int j = 0; j < 4; ++j) acc[i][j] = (f32x4){0.f, 0.f, 0.f, 0.f};
  const u16* Zb = Z + (size_t)b * L * Cin;

  // ---- staging helpers (lambdas keep indexing in one place) ----
  uint4 zr[5];
  auto zs_issue = [&](int c0) {
#pragma unroll
    for (int i = 0; i < 5; ++i) {
      int e = tid + i * 256;
      if (e < 130 * 8) {
        int r = e >> 3, c = e & 7;
        int gl = l0 + r - 1;
        if (gl < 0) gl += L; else if (gl >= L) gl -= L;
        zr[i] = *(const uint4*)(Zb + (size_t)gl * Cin + c0 + c * 8);
      }
    }
  };
  auto zs_write = [&]() {
#pragma unroll
    for (int i = 0; i < 5; ++i) {
      int e = tid + i * 256;
      if (e < 130 * 8) {
        int r = e >> 3, c = e & 7;
        *(uint4*)&Zs[r][(c ^ (r & 7)) * 8] = zr[i];
      }
    }
  };
  auto ws_issue = [&](int t, int c0, int buf) {
    const u16* Wg = Wt + ((size_t)t * Cout + co0) * Cin + c0;
    int c = lane & 7;
#pragma unroll
    for (int i = 0; i < 4; ++i) {
      int rw = (i * 4 + w) * 8 + (lane >> 3);
      gload16(Wg + (size_t)rw * Cin + ((c ^ (rw & 7)) * 8), &Wb[buf][(i * 4 + w) * 8][0]);
    }
  };

  int nchunk = (Cin >> 6) * 3;
  zs_issue(0);
  zs_write();
  ws_issue(0, 0, 0);
  __syncthreads();

  for (int k = 0; k < nchunk; ++k) {
    int t = k % 3;
    int c0 = (k / 3) << 6;
    int cur = k & 1;
    if (k + 1 < nchunk) ws_issue((k + 1) % 3, ((k + 1) / 3) << 6, cur ^ 1);
    bool bndry = (t == 2) && (c0 + 64 < Cin);
    if (bndry) zs_issue(c0 + 64);
#pragma unroll
    for (int ks = 0; ks < 2; ++ks) {
      int s = ks * 4 + g4;   // 16B slot index within row
      bf16x8 af[4], bfr[4];
#pragma unroll
      for (int mi = 0; mi < 4; ++mi) {
        int ra = wr * 64 + mi * 16 + row16 + t;
        af[mi] = *(const bf16x8*)&Zs[ra][(s ^ (ra & 7)) * 8];
      }
#pragma unroll
      for (int ni = 0; ni < 4; ++ni) {
        int rb = wc * 64 + ni * 16 + row16;
        bfr[ni] = *(const bf16x8*)&Wb[cur][rb][(s ^ (rb & 7)) * 8];
      }
#pragma unroll
      for (int mi = 0; mi < 4; ++mi)
#pragma unroll
        for (int ni = 0; ni < 4; ++ni)
          acc[mi][ni] = __builtin_amdgcn_mfma_f32_16x16x32_bf16(
              af[mi], bfr[ni], acc[mi][ni], 0, 0, 0);
    }
    __syncthreads();   // drains next-chunk gload_lds; publishes compute done
    if (bndry) {
      zs_write();
      __syncthreads();
    }
  }

  size_t ob = (size_t)b * L * Cout;
#pragma unroll
  for (int ni = 0; ni < 4; ++ni) {
    int co = co0 + wc * 64 + ni * 16 + row16;
    float bz = bias[co];
#pragma unroll
    for (int mi = 0; mi < 4; ++mi) {
#pragma unroll
      for (int r = 0; r < 4; ++r) {
        int l = l0 + wr * 64 + mi * 16 + g4 * 4 + r;
        float v = acc[mi][ni][r] + bz;
        if (relu) v = fmaxf(v, 0.f);
        out[ob + (size_t)l * osl + (size_t)co * osc] = f2bf(v);
      }
    }
  }
}

// ---------------- fused cross attention, MFMA (unchanged) ----------------
__global__ __launch_bounds__(256, 4) void attn_mfma_kernel(
    const u16* __restrict__ qh, const u16* __restrict__ kh, const u16* __restrict__ vhT,
    const u16* __restrict__ ql, const u16* __restrict__ kl, const u16* __restrict__ vlT,
    u16* __restrict__ ctx) {
  __shared__ u16 Qs[64][72], Ks[64][72], Vts[64][72];
  __shared__ u16 Ps[64][72];   // P[q][k] during PV; reused as Ot[d][q] for epilogue
  __shared__ float rsl[2][2][32];  // [wr][wc][q_local] softmax denominator partials
  int qt = blockIdx.x, h = blockIdx.y, bz = blockIdx.z;
  int b = bz >> 1, br = bz & 1;
  const u16* Q  = br ? ql  : qh;
  const u16* K  = br ? kh  : kl;
  const u16* Vt = br ? vlT : vhT;
  int tid = threadIdx.x;
  int lane = tid & 63, w = tid >> 6, wr = w >> 1, wc = w & 1;
  int row16 = lane & 15, g4 = lane >> 4, k8 = g4 * 8;
  int q0 = qt * 64;
  size_t baseQK = (size_t)b * FEA_ * DM_ + h * 64;
  size_t baseV  = (size_t)b * DM_ * FEA_ + (size_t)(h * 64) * FEA_;
  for (int e = tid; e < 64 * 8; e += 256) {
    int r = e >> 3, c = e & 7;
    *(uint4*)&Qs[r][c * 8] = *(const uint4*)(Q + baseQK + (size_t)(q0 + r) * DM_ + c * 8);
  }
  f32x4 oacc[2][2];
  float rsum[2][4];
#pragma unroll
  for (int i = 0; i < 2; ++i) {
#pragma unroll
    for (int j = 0; j < 2; ++j) oacc[i][j] = (f32x4){0.f, 0.f, 0.f, 0.f};
#pragma unroll
    for (int r = 0; r < 4; ++r) rsum[i][r] = 0.f;
  }
  for (int kt = 0; kt < 8; ++kt) {
    __syncthreads();
    for (int e = tid; e < 64 * 8; e += 256) {
      int r = e >> 3, c = e & 7;
      *(uint4*)&Ks[r][c * 8]  = *(const uint4*)(K + baseQK + (size_t)(kt * 64 + r) * DM_ + c * 8);
      *(uint4*)&Vts[r][c * 8] = *(const uint4*)(Vt + baseV + (size_t)r * FEA_ + kt * 64 + c * 8);
    }
    __syncthreads();
    f32x4 sacc[2][2];
#pragma unroll
    for (int i = 0; i < 2; ++i)
#pragma unroll
      for (int j = 0; j < 2; ++j) sacc[i][j] = (f32x4){0.f, 0.f, 0.f, 0.f};
#pragma unroll
    for (int ks = 0; ks < 2; ++ks) {
      int k0 = ks * 32 + k8;
      bf16x8 a0 = *(const bf16x8*)&Qs[wr * 32 + row16][k0];
      bf16x8 a1 = *(const bf16x8*)&Qs[wr * 32 + 16 + row16][k0];
      bf16x8 b0 = *(const bf16x8*)&Ks[wc * 32 + row16][k0];
      bf16x8 b1 = *(const bf16x8*)&Ks[wc * 32 + 16 + row16][k0];
      sacc[0][0] = __builtin_amdgcn_mfma_f32_16x16x32_bf16(a0, b0, sacc[0][0], 0, 0, 0);
      sacc[0][1] = __builtin_amdgcn_mfma_f32_16x16x32_bf16(a0, b1, sacc[0][1], 0, 0, 0);
      sacc[1][0] = __builtin_amdgcn_mfma_f32_16x16x32_bf16(a1, b0, sacc[1][0], 0, 0, 0);
      sacc[1][1] = __builtin_amdgcn_mfma_f32_16x16x32_bf16(a1, b1, sacc[1][1], 0, 0, 0);
    }
#pragma unroll
    for (int mi = 0; mi < 2; ++mi)
#pragma unroll
      for (int ni = 0; ni < 2; ++ni)
#pragma unroll
        for (int r = 0; r < 4; ++r) {
          float p = __expf(sacc[mi][ni][r] * 0.25f);
          rsum[mi][r] += p;
          Ps[wr * 32 + mi * 16 + g4 * 4 + r][wc * 32 + ni * 16 + row16] = f2bf(p);
        }
    __syncthreads();
#pragma unroll
    for (int ks = 0; ks < 2; ++ks) {
      int k0 = ks * 32 + k8;
      bf16x8 a0 = *(const bf16x8*)&Ps[wr * 32 + row16][k0];
      bf16x8 a1 = *(const bf16x8*)&Ps[wr * 32 + 16 + row16][k0];
      bf16x8 b0 = *(const bf16x8*)&Vts[wc * 32 + row16][k0];
      bf16x8 b1 = *(const bf16x8*)&Vts[wc * 32 + 16 + row16][k0];
      oacc[0][0] = __builtin_amdgcn_mfma_f32_16x16x32_bf16(a0, b0, oacc[0][0], 0, 0, 0);
      oacc[0][1] = __builtin_amdgcn_mfma_f32_16x16x32_bf16(a0, b1, oacc[0][1], 0, 0, 0);
      oacc[1][0] = __builtin_amdgcn_mfma_f32_16x16x32_bf16(a1, b0, oacc[1][0], 0, 0, 0);
      oacc[1][1] = __builtin_amdgcn_mfma_f32_16x16x32_bf16(a1, b1, oacc[1][1], 0, 0, 0);
    }
  }
#pragma unroll
  for (int mi = 0; mi < 2; ++mi)
#pragma unroll
    for (int r = 0; r < 4; ++r) {
#pragma unroll
      for (int m = 1; m < 16; m <<= 1) rsum[mi][r] += __shfl_xor(rsum[mi][r], m);
    }
  if (row16 == 0) {
#pragma unroll
    for (int mi = 0; mi < 2; ++mi)
#pragma unroll
      for (int r = 0; r < 4; ++r) rsl[wr][wc][mi * 16 + g4 * 4 + r] = rsum[mi][r];
  }
  __syncthreads();
#pragma unroll
  for (int mi = 0; mi < 2; ++mi)
#pragma unroll
    for (int ni = 0; ni < 2; ++ni)
#pragma unroll
      for (int r = 0; r < 4; ++r) {
        int qq = mi * 16 + g4 * 4 + r;
        float denom = rsl[wr][0][qq] + rsl[wr][1][qq];
        float o = oacc[mi][ni][r] / denom;
        Ps[wc * 32 + ni * 16 + row16][wr * 32 + qq] = f2bf(o);
      }
  __syncthreads();
  for (int e = tid; e < 64 * 8; e += 256) {
    int r = e >> 3, c = e & 7;
    size_t dst = ((size_t)b * DM_ + h * 64 + r) * (2 * FEA_) + br * 512 + q0 + c * 8;
    *(uint4*)(ctx + dst) = *(const uint4*)&Ps[r][c * 8];
  }
}

// ---------------- LayerNorm over last axis (+optional f32 residual out) ----------------
template <int RESID>
__global__ void ln_kernel(const u16* __restrict__ in, const float* __restrict__ g,
                          const float* __restrict__ beta, const float* __restrict__ resid,
                          void* __restrict__ outp, int C) {
  int row = blockIdx.x;
  int tid = threadIdx.x;
  const u16* p = in + (size_t)row * C;
  float s = 0.f, ss = 0.f;
  for (int c = tid; c < C; c += 256) {
    float v = bf2f(p[c]);
    s += v; ss += v * v;
  }
#pragma unroll
  for (int m = 1; m < 64; m <<= 1) { s += __shfl_xor(s, m); ss += __shfl_xor(ss, m); }
  __shared__ float red[2][4];
  int wid = tid >> 6, lane = tid & 63;
  if (lane == 0) { red[0][wid] = s; red[1][wid] = ss; }
  __syncthreads();
  s  = red[0][0] + red[0][1] + red[0][2] + red[0][3];
  ss = red[1][0] + red[1][1] + red[1][2] + red[1][3];
  float m  = s / C;
  float var = ss / C - m * m;
  float inv = rsqrtf(var + 1e-5f);
  for (int c = tid; c < C; c += 256) {
    float v = (bf2f(p[c]) - m) * inv * g[c] + beta[c];
    if (RESID) ((float*)outp)[(size_t)row * C + c] = v + resid[(size_t)row * C + c];
    else       ((u16*)outp)[(size_t)row * C + c]   = f2bf(v);
  }
}

extern "C" void kernel_launch(void* const* d_in, const int* in_sizes, int n_in,
                              void* d_out, int out_size, void* d_ws, size_t ws_size,
                              hipStream_t stream) {
  (void)in_sizes; (void)n_in; (void)out_size; (void)ws_size;
  const float* x      = (const float*)d_in[0];
  const float* Wq     = (const float*)d_in[1];
  const float* bq     = (const float*)d_in[2];
  const float* Wk     = (const float*)d_in[3];
  const float* bk     = (const float*)d_in[4];
  const float* Wv     = (const float*)d_in[5];
  const float* bv     = (const float*)d_in[6];
  const float* uns_w  = (const float*)d_in[7];
  const float* uns_b  = (const float*)d_in[8];
  const float* cv_w1  = (const float*)d_in[9];
  const float* cv_b1  = (const float*)d_in[10];
  const float* cv_w2  = (const float*)d_in[11];
  const float* cv_b2  = (const float*)d_in[12];
  const float* cv_g   = (const float*)d_in[13];
  const float* cv_beta= (const float*)d_in[14];
  const float* up_w1  = (const float*)d_in[15];
  const float* up_b1  = (const float*)d_in[16];
  const float* up_w2  = (const float*)d_in[17];
  const float* up_b2  = (const float*)d_in[18];
  const float* up_g   = (const float*)d_in[19];
  const float* up_beta= (const float*)d_in[20];

  // ---- workspace plan (peak 112 MiB of d_ws; d_out doubles as scratch) ----
  char* ws = (char*)d_ws;
  const size_t MB = 1ull << 20;
  u16* x1    = (u16*)(ws + 0);
  u16* x2    = (u16*)(ws + 8 * MB);
  u16* qhb   = (u16*)(ws + 16 * MB);
  u16* khb   = (u16*)(ws + 32 * MB);
  u16* vhb   = (u16*)(ws + 48 * MB);   // stored TRANSPOSED: [b][d][fea]
  u16* qlb   = (u16*)(ws + 64 * MB);
  u16* klb   = (u16*)(ws + 80 * MB);
  u16* vlb   = (u16*)(ws + 96 * MB);   // stored TRANSPOSED: [b][d][fea]
  u16* wt_proj = (u16*)d_out;
  u16* ctx   = (u16*)d_out;
  u16* wt_uns = (u16*)(ws + 0);
  u16* ctx2  = (u16*)(ws + 16 * MB);
  u16* wt_cv1 = (u16*)(ws + 32 * MB);
  u16* h1    = (u16*)(ws + 56 * MB);
  u16* wt_cv2 = (u16*)(ws + 32 * MB);
  u16* h2    = (u16*)(ws + 0);
  u16* ctx3  = (u16*)(ws + 8 * MB);
  u16* wt_up1 = (u16*)(ws + 16 * MB);
  u16* h3    = (u16*)(ws + 32 * MB);
  u16* wt_up2 = (u16*)(ws + 64 * MB);
  u16* h4    = (u16*)(ws + 16 * MB);

  dwt_kernel<<<(B_ * FEA_ * HALF_ + 255) / 256, 256, 0, stream>>>(x, x1, x2, B_ * FEA_ * HALF_);

  auto wtr = [&](const float* w, u16* wt, int Cout, int Cin) {
    wtrans_kernel<<<(Cout * Cin * 3 + 255) / 256, 256, 0, stream>>>(w, wt, Cout, Cin);
  };
  auto conv = [&](const u16* Z, const u16* wt, const float* bias, u16* out, int L,
                  int Cin, int Cout, int osl, int osc, int relu) {
    conv_mfma_kernel<<<dim3(L / 128, Cout / 128, B_), 256, 0, stream>>>(
        Z, wt, bias, out, L, Cin, Cout, osl, osc, relu);
  };

  // projections (shared weights across both DWT branches); V written transposed
  wtr(Wq, wt_proj, DM_, HALF_);
  conv(x1, wt_proj, bq, qhb, FEA_, HALF_, DM_, DM_, 1, 0);
  conv(x2, wt_proj, bq, qlb, FEA_, HALF_, DM_, DM_, 1, 0);
  wtr(Wk, wt_proj, DM_, HALF_);
  conv(x1, wt_proj, bk, khb, FEA_, HALF_, DM_, DM_, 1, 0);
  conv(x2, wt_proj, bk, klb, FEA_, HALF_, DM_, DM_, 1, 0);
  wtr(Wv, wt_proj, DM_, HALF_);
  conv(x1, wt_proj, bv, vhb, FEA_, HALF_, DM_, 1, FEA_, 0);
  conv(x2, wt_proj, bv, vlb, FEA_, HALF_, DM_, 1, FEA_, 0);

  attn_mfma_kernel<<<dim3(8, 16, 32), 256, 0, stream>>>(qhb, khb, vhb, qlb, klb, vlb, ctx);

  // unsqueeze conv: conv along d axis, channels 2F->F, transposed write -> ctx2[b][f][d]
  wtr(uns_w, wt_uns, FEA_, 2 * FEA_);
  conv(ctx, wt_uns, uns_b, ctx2, DM_, 2 * FEA_, FEA_, 1, DM_, 0);

  // Convlayer: D_MODEL -> D_FF -> HALF (conv along fea axis), then LN
  wtr(cv_w1, wt_cv1, DFF_, DM_);
  conv(ctx2, wt_cv1, cv_b1, h1, FEA_, DM_, DFF_, DFF_, 1, 1);
  wtr(cv_w2, wt_cv2, HALF_, DFF_);
  conv(h1, wt_cv2, cv_b2, h2, FEA_, DFF_, HALF_, HALF_, 1, 0);
  ln_kernel<0><<<B_ * FEA_, 256, 0, stream>>>(h2, cv_g, cv_beta, nullptr, ctx3, HALF_);

  // upsizeConvlayer: HALF -> D_FF -> D_MODEL, then LN + residual
  wtr(up_w1, wt_up1, DFF_, HALF_);
  conv(ctx3, wt_up1, up_b1, h3, FEA_, HALF_, DFF_, DFF_, 1, 1);
  wtr(up_w2, wt_up2, DM_, DFF_);
  conv(h3, wt_up2, up_b2, h4, FEA_, DFF_, DM_, DM_, 1, 0);
  ln_kernel<1><<<B_ * FEA_, 256, 0, stream>>>(h4, up_g, up_beta, x, d_out, DM_);
}